// Round 1
// baseline (739.215 us; speedup 1.0000x reference)
//
#include <hip/hip_runtime.h>
#include <hip/hip_bf16.h>

// FluxJointAttention on MI355X (gfx950), bf16 MFMA pipeline.
// Stages: cvt X -> bf16 | transpose-cvt W -> bf16 [N][K] | QKV GEMM + bias +
// RMSnorm + RoPE epilogue -> Q,K [h][s][d], V^T [h][d][s] | flash attention ->
// AO [s][3072] bf16 | out-proj GEMM + bias -> fp32 d_out.

typedef __attribute__((ext_vector_type(8))) short s16x8;
typedef __attribute__((ext_vector_type(8))) unsigned short u16x8;
typedef __attribute__((ext_vector_type(4))) float f32x4;

#define DEV static __device__ __forceinline__

#define S_TOT 2560
#define DIMC 3072
#define NQKV 9216

DEV unsigned short f2bf(float f) {
  union { float f; unsigned u; } v; v.f = f;
  return (unsigned short)((v.u + 0x7fffu + ((v.u >> 16) & 1u)) >> 16);
}
DEV float bf2f(unsigned short h) {
  union { unsigned u; float f; } v; v.u = ((unsigned)h) << 16;
  return v.f;
}
DEV void gload16(const void* g, void* l) {
  __builtin_amdgcn_global_load_lds((__attribute__((address_space(1))) void*)g,
                                   (__attribute__((address_space(3))) void*)l,
                                   16, 0, 0);
}

// ---------------- conversion kernels ----------------

__global__ __launch_bounds__(256) void cvt_bf16_k(const float* __restrict__ in,
                                                  unsigned short* __restrict__ out,
                                                  int n8) {
  int i = blockIdx.x * 256 + threadIdx.x;
  if (i >= n8) return;
  const float4* p = (const float4*)(in + (size_t)i * 8);
  float4 a = p[0], b = p[1];
  u16x8 u;
  u[0] = f2bf(a.x); u[1] = f2bf(a.y); u[2] = f2bf(a.z); u[3] = f2bf(a.w);
  u[4] = f2bf(b.x); u[5] = f2bf(b.y); u[6] = f2bf(b.z); u[7] = f2bf(b.w);
  *(u16x8*)(out + (size_t)i * 8) = u;
}

// W (K x N) f32 row-major -> WT (N x K) bf16 row-major. 64x64 tiles.
__global__ __launch_bounds__(256) void transpose_cvt(const float* __restrict__ W,
                                                     unsigned short* __restrict__ WT,
                                                     int K, int N) {
  __shared__ float tile[64][65];
  const int t = threadIdx.x;
  const int n0 = blockIdx.x * 64, k0 = blockIdx.y * 64;
#pragma unroll
  for (int rep = 0; rep < 4; ++rep) {
    int idx = rep * 256 + t;
    int r = idx >> 4, c4 = (idx & 15) * 4;
    float4 v = *(const float4*)&W[(size_t)(k0 + r) * N + n0 + c4];
    tile[r][c4] = v.x; tile[r][c4 + 1] = v.y; tile[r][c4 + 2] = v.z; tile[r][c4 + 3] = v.w;
  }
  __syncthreads();
#pragma unroll
  for (int rep = 0; rep < 2; ++rep) {
    int idx = rep * 256 + t;
    int j = idx >> 3, i0 = (idx & 7) * 8;
    u16x8 u;
#pragma unroll
    for (int i = 0; i < 8; i++) u[i] = f2bf(tile[i0 + i][j]);
    *(u16x8*)&WT[(size_t)(n0 + j) * K + k0 + i0] = u;
  }
}

// ---------------- GEMM core (BM=128, BN=128, BK=64, 4 waves) ----------------
// A: [M][3072] bf16 row-major (pre-offset to tile row 0)
// B: [N][3072] bf16 row-major (pre-offset to tile row 0) -- i.e. W^T
// LDS tiles [128 rows][64 k] bf16, rows 128B, XOR-swizzle byte^=((row&7)<<4)
// applied on the *global source* (gload_lds writes linearly) and on ds_read.

struct StageSmem {
  unsigned short A[128 * 64];
  unsigned short B[128 * 64];
};

DEV void gemm_core(const unsigned short* __restrict__ Ap,
                   const unsigned short* __restrict__ Bp,
                   StageSmem* sm, int tid, f32x4 (&acc)[4][4]) {
  const int wave = tid >> 6, lane = tid & 63;
  const int wr = wave >> 1, wc = wave & 1;
  const int lh = lane >> 4, ll = lane & 15;
  const int row_s = tid >> 3;          // 0..31 per staging step
  const int kbp = (tid & 7) * 16;      // physical 16B slot within row

  for (int kt = 0; kt < 48; ++kt) {
    __syncthreads();
#pragma unroll
    for (int st = 0; st < 4; ++st) {
      int row = st * 32 + row_s;
      int kb = kbp ^ ((row & 7) << 4);  // logical byte within 128B row
      gload16((const char*)(Ap + (size_t)row * DIMC) + kt * 128 + kb,
              (char*)sm->A + st * 4096 + tid * 16);
      gload16((const char*)(Bp + (size_t)row * DIMC) + kt * 128 + kb,
              (char*)sm->B + st * 4096 + tid * 16);
    }
    __syncthreads();
#pragma unroll
    for (int ks = 0; ks < 2; ++ks) {
      s16x8 a[4], b[4];
#pragma unroll
      for (int f = 0; f < 4; ++f) {
        int ar = wr * 64 + f * 16 + ll;
        a[f] = *(const s16x8*)((const char*)sm->A + ar * 128 +
                               ((ks * 64 + lh * 16) ^ ((ar & 7) << 4)));
        int br = wc * 64 + f * 16 + ll;
        b[f] = *(const s16x8*)((const char*)sm->B + br * 128 +
                               ((ks * 64 + lh * 16) ^ ((br & 7) << 4)));
      }
#pragma unroll
      for (int i = 0; i < 4; i++)
#pragma unroll
        for (int j = 0; j < 4; j++)
          acc[i][j] = __builtin_amdgcn_mfma_f32_16x16x32_bf16(a[i], b[j], acc[i][j], 0, 0, 0);
    }
  }
  __syncthreads();
}

// ---------------- QKV GEMM + bias + RMSnorm + RoPE epilogue ----------------

union QkvSmem {
  StageSmem st;
  unsigned short ctile[128 * 136];  // [128 rows][128 cols], pad to 136
};

__global__ __launch_bounds__(256, 2) void qkv_gemm(
    const unsigned short* __restrict__ X, const unsigned short* __restrict__ WT,
    const float* __restrict__ bias, const float* __restrict__ wq,
    const float* __restrict__ wk, const float* __restrict__ freqs,
    unsigned short* __restrict__ Qb, unsigned short* __restrict__ Kb,
    unsigned short* __restrict__ Vt, int s_off) {
  __shared__ QkvSmem sm;
  const int tid = threadIdx.x;
  const int m0 = blockIdx.y * 128, n0 = blockIdx.x * 128;
  f32x4 acc[4][4] = {};
  gemm_core(X + (size_t)m0 * DIMC, WT + (size_t)n0 * DIMC, &sm.st, tid, acc);

  {  // acc + bias -> ctile (bf16)
    const int wave = tid >> 6, lane = tid & 63;
    const int wr = wave >> 1, wc = wave & 1, lh = lane >> 4, ll = lane & 15;
#pragma unroll
    for (int fn = 0; fn < 4; ++fn) {
      int c = wc * 64 + fn * 16 + ll;
      float bv = bias[n0 + c];
#pragma unroll
      for (int fm = 0; fm < 4; ++fm)
#pragma unroll
        for (int j = 0; j < 4; j++) {
          int r = wr * 64 + fm * 16 + lh * 4 + j;
          sm.ctile[r * 136 + c] = f2bf(acc[fm][fn][j] + bv);
        }
    }
  }
  __syncthreads();

  const int qkv_idx = blockIdx.x / 24;   // 24 n-tiles per {q,k,v}
  const int head = blockIdx.x % 24;

  if (qkv_idx == 2) {
    // V: transposed store Vt[h][d][s]  (256B contiguous per (d,tile) chunk)
    const int sg0 = s_off + m0;
#pragma unroll
    for (int half = 0; half < 2; ++half) {
      int d = half * 64 + (tid >> 2);
      int t0 = (tid & 3) * 32;
      size_t obase = (size_t)(head * 128 + d) * S_TOT + sg0 + t0;
#pragma unroll
      for (int v = 0; v < 4; ++v) {
        u16x8 u;
#pragma unroll
        for (int i = 0; i < 8; i++) u[i] = sm.ctile[(t0 + v * 8 + i) * 136 + d];
        *(u16x8*)&Vt[obase + v * 8] = u;
      }
    }
  } else {
    // Q/K: RMS norm over 128 cols + RoPE, store [h][s][d]
    const float* wn = (qkv_idx == 0) ? wq : wk;
    unsigned short* Ob = (qkv_idx == 0) ? Qb : Kb;
    const int row = tid >> 1, half = tid & 1;
    const int sg = s_off + m0 + row;
    float x[64];
    float ss = 0.f;
#pragma unroll
    for (int i = 0; i < 64; i++) {
      float v = bf2f(sm.ctile[row * 136 + half * 64 + i]);
      x[i] = v; ss += v * v;
    }
    ss += __shfl_xor(ss, 1);
    const float rn = rsqrtf(ss * (1.f / 128.f) + 1e-6f);
    const float* fr = freqs + (size_t)sg * 256 + half * 128;  // 64 pairs * 4 f32 / row
    unsigned short o[64];
#pragma unroll
    for (int p = 0; p < 32; ++p) {
      float w0 = wn[half * 64 + 2 * p], w1 = wn[half * 64 + 2 * p + 1];
      float y0 = x[2 * p] * rn * w0, y1 = x[2 * p + 1] * rn * w1;
      float f00 = fr[p * 4], f01 = fr[p * 4 + 1], f10 = fr[p * 4 + 2], f11 = fr[p * 4 + 3];
      o[2 * p] = f2bf(f00 * y0 + f01 * y1);
      o[2 * p + 1] = f2bf(f10 * y0 + f11 * y1);
    }
    size_t ob = ((size_t)head * S_TOT + sg) * 128 + half * 64;
#pragma unroll
    for (int v = 0; v < 8; ++v) {
      u16x8 u;
#pragma unroll
      for (int i = 0; i < 8; i++) u[i] = o[v * 8 + i];
      *(u16x8*)&Ob[ob + v * 8] = u;
    }
  }
}

// ---------------- flash attention ----------------
// 4 waves x 16 q-rows, KV tiles of 64, full (unmasked) softmax over 2560 keys.

__global__ __launch_bounds__(256, 2) void attn_k(
    const unsigned short* __restrict__ Qb, const unsigned short* __restrict__ Kb,
    const unsigned short* __restrict__ Vt, unsigned short* __restrict__ AO) {
  __shared__ alignas(128) unsigned short Ks[64 * 128];  // [key][d], swizzled
  __shared__ alignas(128) unsigned short Vs[128 * 64];  // [d][key], swizzled
  __shared__ alignas(128) unsigned short Ps[4][16 * 72]; // per-wave P [q][key], pad 72

  const int tid = threadIdx.x, wave = tid >> 6, lane = tid & 63;
  const int lh = lane >> 4, ll = lane & 15;
  const int qt = blockIdx.x, h = blockIdx.y;
  const float scale = 0.08838834764831845f;  // 1/sqrt(128)

  s16x8 qf[4];
  {
    size_t qbase = ((size_t)h * S_TOT + qt * 64 + wave * 16 + ll) * 128;
#pragma unroll
    for (int ks = 0; ks < 4; ks++) qf[ks] = *(const s16x8*)&Qb[qbase + ks * 32 + lh * 8];
  }
  float m_r[4], l_r[4];
  f32x4 o[8] = {};
#pragma unroll
  for (int j = 0; j < 4; j++) { m_r[j] = -1e30f; l_r[j] = 0.f; }

  for (int kt = 0; kt < 40; ++kt) {
    __syncthreads();
    {
      const int k0 = kt * 64;
#pragma unroll
      for (int st = 0; st < 4; ++st) {
        int row = st * 16 + (tid >> 4);                    // key row, 256B
        int kb = ((tid & 15) * 16) ^ ((row & 7) << 4);
        gload16((const char*)(Kb + ((size_t)h * S_TOT + k0 + row) * 128) + kb,
                (char*)Ks + st * 4096 + tid * 16);
        int vrow = st * 32 + (tid >> 3);                   // d row, 128B
        int vkb = ((tid & 7) * 16) ^ ((vrow & 7) << 4);
        gload16((const char*)(Vt + (size_t)(h * 128 + vrow) * S_TOT + k0) + vkb,
                (char*)Vs + st * 4096 + tid * 16);
      }
    }
    __syncthreads();

    f32x4 sc[4] = {};
#pragma unroll
    for (int kb = 0; kb < 4; kb++) {
      int krow = kb * 16 + ll;
#pragma unroll
      for (int ks = 0; ks < 4; ks++) {
        s16x8 bf = *(const s16x8*)((const char*)Ks + krow * 256 +
                                   ((ks * 64 + lh * 16) ^ ((krow & 7) << 4)));
        sc[kb] = __builtin_amdgcn_mfma_f32_16x16x32_bf16(qf[ks], bf, sc[kb], 0, 0, 0);
      }
    }
    // online softmax (rows r = lh*4+j, cols = kb*16+ll)
    float al[4];
#pragma unroll
    for (int j = 0; j < 4; j++) {
      float v = fmaxf(fmaxf(sc[0][j], sc[1][j]), fmaxf(sc[2][j], sc[3][j]));
#pragma unroll
      for (int m = 1; m < 16; m <<= 1) v = fmaxf(v, __shfl_xor(v, m));
      float mn = fmaxf(m_r[j], v * scale);
      al[j] = __expf(m_r[j] - mn);
      m_r[j] = mn;
    }
    float psum[4] = {0.f, 0.f, 0.f, 0.f};
    unsigned short pbf[4][4];
#pragma unroll
    for (int kb = 0; kb < 4; kb++)
#pragma unroll
      for (int j = 0; j < 4; j++) {
        float p = __expf(sc[kb][j] * scale - m_r[j]);
        psum[j] += p;
        pbf[kb][j] = f2bf(p);
      }
#pragma unroll
    for (int j = 0; j < 4; j++) {
      float s = psum[j];
#pragma unroll
      for (int m = 1; m < 16; m <<= 1) s += __shfl_xor(s, m);
      l_r[j] = l_r[j] * al[j] + s;
    }
#pragma unroll
    for (int nb = 0; nb < 8; nb++)
#pragma unroll
      for (int j = 0; j < 4; j++) o[nb][j] *= al[j];

    unsigned short* P = &Ps[wave][0];
#pragma unroll
    for (int kb = 0; kb < 4; kb++)
#pragma unroll
      for (int j = 0; j < 4; j++)
        P[(lh * 4 + j) * 72 + kb * 16 + ll] = pbf[kb][j];

#pragma unroll
    for (int ks = 0; ks < 2; ks++) {
      s16x8 pa = *(const s16x8*)&P[ll * 72 + ks * 32 + lh * 8];
#pragma unroll
      for (int nb = 0; nb < 8; nb++) {
        int vrow = nb * 16 + ll;
        s16x8 vb = *(const s16x8*)((const char*)Vs + vrow * 128 +
                                   ((ks * 64 + lh * 16) ^ ((vrow & 7) << 4)));
        o[nb] = __builtin_amdgcn_mfma_f32_16x16x32_bf16(pa, vb, o[nb], 0, 0, 0);
      }
    }
  }
  // write AO [s][h*128 + d]
  {
    int s0 = qt * 64 + wave * 16;
#pragma unroll
    for (int j = 0; j < 4; j++) {
      float inv = 1.0f / l_r[j];
      size_t base = (size_t)(s0 + lh * 4 + j) * DIMC + h * 128;
#pragma unroll
      for (int nb = 0; nb < 8; nb++) AO[base + nb * 16 + ll] = f2bf(o[nb][j] * inv);
    }
  }
}

// ---------------- out projection ----------------

__global__ __launch_bounds__(256, 2) void out_gemm(
    const unsigned short* __restrict__ A, const unsigned short* __restrict__ WT,
    const float* __restrict__ bias, float* __restrict__ C) {
  __shared__ StageSmem sm;
  const int tid = threadIdx.x;
  const int m0 = blockIdx.y * 128, n0 = blockIdx.x * 128;
  f32x4 acc[4][4] = {};
  gemm_core(A + (size_t)m0 * DIMC, WT + (size_t)n0 * DIMC, &sm, tid, acc);
  const int wave = tid >> 6, lane = tid & 63;
  const int wr = wave >> 1, wc = wave & 1, lh = lane >> 4, ll = lane & 15;
#pragma unroll
  for (int fn = 0; fn < 4; ++fn) {
    int c = n0 + wc * 64 + fn * 16 + ll;
    float bv = bias[c];
#pragma unroll
    for (int fm = 0; fm < 4; ++fm)
#pragma unroll
      for (int j = 0; j < 4; j++) {
        int r = m0 + wr * 64 + fm * 16 + lh * 4 + j;
        C[(size_t)r * DIMC + c] = acc[fm][fn][j] + bv;
      }
  }
}

// ---------------- launcher ----------------

extern "C" void kernel_launch(void* const* d_in, const int* in_sizes, int n_in,
                              void* d_out, int out_size, void* d_ws, size_t ws_size,
                              hipStream_t stream) {
  (void)in_sizes; (void)n_in; (void)out_size; (void)ws_size;
  const float* Xa = (const float*)d_in[0];
  const float* Xb = (const float*)d_in[1];
  const float* freqs = (const float*)d_in[2];
  const float* Wqkv_a = (const float*)d_in[3];
  const float* bqkv_a = (const float*)d_in[4];
  const float* Wqkv_b = (const float*)d_in[5];
  const float* bqkv_b = (const float*)d_in[6];
  const float* wq_a = (const float*)d_in[7];
  const float* wk_a = (const float*)d_in[8];
  const float* wq_b = (const float*)d_in[9];
  const float* wk_b = (const float*)d_in[10];
  const float* Wout_a = (const float*)d_in[11];
  const float* bout_a = (const float*)d_in[12];
  const float* Wout_b = (const float*)d_in[13];
  const float* bout_b = (const float*)d_in[14];
  float* out = (float*)d_out;

  char* ws = (char*)d_ws;
  unsigned short* WTa  = (unsigned short*)ws; ws += (size_t)NQKV * DIMC * 2;
  unsigned short* WTb  = (unsigned short*)ws; ws += (size_t)NQKV * DIMC * 2;
  unsigned short* WoTa = (unsigned short*)ws; ws += (size_t)DIMC * DIMC * 2;
  unsigned short* WoTb = (unsigned short*)ws; ws += (size_t)DIMC * DIMC * 2;
  unsigned short* Xa16 = (unsigned short*)ws; ws += (size_t)2048 * DIMC * 2;
  unsigned short* Xb16 = (unsigned short*)ws; ws += (size_t)512 * DIMC * 2;
  unsigned short* Qb   = (unsigned short*)ws; ws += (size_t)24 * S_TOT * 128 * 2;
  unsigned short* Kbf  = (unsigned short*)ws; ws += (size_t)24 * S_TOT * 128 * 2;
  unsigned short* Vt   = (unsigned short*)ws; ws += (size_t)24 * S_TOT * 128 * 2;
  unsigned short* AO   = (unsigned short*)ws; ws += (size_t)S_TOT * DIMC * 2;

  cvt_bf16_k<<<dim3(2048 * DIMC / 8 / 256), dim3(256), 0, stream>>>(Xa, Xa16, 2048 * DIMC / 8);
  cvt_bf16_k<<<dim3(512 * DIMC / 8 / 256), dim3(256), 0, stream>>>(Xb, Xb16, 512 * DIMC / 8);
  transpose_cvt<<<dim3(NQKV / 64, DIMC / 64), dim3(256), 0, stream>>>(Wqkv_a, WTa, DIMC, NQKV);
  transpose_cvt<<<dim3(NQKV / 64, DIMC / 64), dim3(256), 0, stream>>>(Wqkv_b, WTb, DIMC, NQKV);
  transpose_cvt<<<dim3(DIMC / 64, DIMC / 64), dim3(256), 0, stream>>>(Wout_a, WoTa, DIMC, DIMC);
  transpose_cvt<<<dim3(DIMC / 64, DIMC / 64), dim3(256), 0, stream>>>(Wout_b, WoTb, DIMC, DIMC);

  qkv_gemm<<<dim3(72, 16), dim3(256), 0, stream>>>(Xa16, WTa, bqkv_a, wq_a, wk_a, freqs,
                                                   Qb, Kbf, Vt, 512);
  qkv_gemm<<<dim3(72, 4), dim3(256), 0, stream>>>(Xb16, WTb, bqkv_b, wq_b, wk_b, freqs,
                                                  Qb, Kbf, Vt, 0);

  attn_k<<<dim3(40, 24), dim3(256), 0, stream>>>(Qb, Kbf, Vt, AO);

  out_gemm<<<dim3(24, 16), dim3(256), 0, stream>>>(AO + (size_t)512 * DIMC, WoTa, bout_a, out);
  out_gemm<<<dim3(24, 4), dim3(256), 0, stream>>>(AO, WoTb, bout_b, out + (size_t)2048 * DIMC);
}

// Round 2
// 628.058 us; speedup vs baseline: 1.1770x; 1.1770x over previous
//
#include <hip/hip_runtime.h>
#include <hip/hip_bf16.h>

// FluxJointAttention on MI355X (gfx950), bf16 MFMA pipeline.
// Round 2: attn_k rewritten — 32 q-rows/wave (B-frag reuse), 32x32 PV MFMA,
// DPP softmax reduces (off the LDS pipe), K dbuf + V top-staged, defer-max.

typedef __attribute__((ext_vector_type(8))) short s16x8;
typedef __attribute__((ext_vector_type(8))) unsigned short u16x8;
typedef __attribute__((ext_vector_type(4))) float f32x4;
typedef __attribute__((ext_vector_type(16))) float f32x16;

#define DEV static __device__ __forceinline__

#define S_TOT 2560
#define DIMC 3072
#define NQKV 9216

DEV unsigned short f2bf(float f) {
  union { float f; unsigned u; } v; v.f = f;
  return (unsigned short)((v.u + 0x7fffu + ((v.u >> 16) & 1u)) >> 16);
}
DEV float bf2f(unsigned short h) {
  union { unsigned u; float f; } v; v.u = ((unsigned)h) << 16;
  return v.f;
}
DEV void gload16(const void* g, void* l) {
  __builtin_amdgcn_global_load_lds((__attribute__((address_space(1))) void*)g,
                                   (__attribute__((address_space(3))) void*)l,
                                   16, 0, 0);
}
DEV float exp2_fast(float x) {
#if __has_builtin(__builtin_amdgcn_exp2f)
  return __builtin_amdgcn_exp2f(x);
#else
  return __expf(x * 0.69314718056f);
#endif
}
template <int CTRL>
DEV float dppf(float x) {
  return __int_as_float(__builtin_amdgcn_update_dpp(0, __float_as_int(x), CTRL, 0xf, 0xf, true));
}
// 16-lane reduces, pure VALU (DPP): xor1, xor2, half-mirror, mirror.
DEV float rowmax16(float x) {
  x = fmaxf(x, dppf<0xB1>(x));
  x = fmaxf(x, dppf<0x4E>(x));
  x = fmaxf(x, dppf<0x141>(x));
  x = fmaxf(x, dppf<0x140>(x));
  return x;
}
DEV float rowsum16(float x) {
  x += dppf<0xB1>(x);
  x += dppf<0x4E>(x);
  x += dppf<0x141>(x);
  x += dppf<0x140>(x);
  return x;
}

// ---------------- conversion kernels ----------------

__global__ __launch_bounds__(256) void cvt_bf16_k(const float* __restrict__ in,
                                                  unsigned short* __restrict__ out,
                                                  int n8) {
  int i = blockIdx.x * 256 + threadIdx.x;
  if (i >= n8) return;
  const float4* p = (const float4*)(in + (size_t)i * 8);
  float4 a = p[0], b = p[1];
  u16x8 u;
  u[0] = f2bf(a.x); u[1] = f2bf(a.y); u[2] = f2bf(a.z); u[3] = f2bf(a.w);
  u[4] = f2bf(b.x); u[5] = f2bf(b.y); u[6] = f2bf(b.z); u[7] = f2bf(b.w);
  *(u16x8*)(out + (size_t)i * 8) = u;
}

// W (K x N) f32 row-major -> WT (N x K) bf16 row-major. 64x64 tiles.
__global__ __launch_bounds__(256) void transpose_cvt(const float* __restrict__ W,
                                                     unsigned short* __restrict__ WT,
                                                     int K, int N) {
  __shared__ float tile[64][65];
  const int t = threadIdx.x;
  const int n0 = blockIdx.x * 64, k0 = blockIdx.y * 64;
#pragma unroll
  for (int rep = 0; rep < 4; ++rep) {
    int idx = rep * 256 + t;
    int r = idx >> 4, c4 = (idx & 15) * 4;
    float4 v = *(const float4*)&W[(size_t)(k0 + r) * N + n0 + c4];
    tile[r][c4] = v.x; tile[r][c4 + 1] = v.y; tile[r][c4 + 2] = v.z; tile[r][c4 + 3] = v.w;
  }
  __syncthreads();
#pragma unroll
  for (int rep = 0; rep < 2; ++rep) {
    int idx = rep * 256 + t;
    int j = idx >> 3, i0 = (idx & 7) * 8;
    u16x8 u;
#pragma unroll
    for (int i = 0; i < 8; i++) u[i] = f2bf(tile[i0 + i][j]);
    *(u16x8*)&WT[(size_t)(n0 + j) * K + k0 + i0] = u;
  }
}

// ---------------- GEMM core (BM=128, BN=128, BK=64, 4 waves) ----------------

struct StageSmem {
  unsigned short A[128 * 64];
  unsigned short B[128 * 64];
};

DEV void gemm_core(const unsigned short* __restrict__ Ap,
                   const unsigned short* __restrict__ Bp,
                   StageSmem* sm, int tid, f32x4 (&acc)[4][4]) {
  const int wave = tid >> 6, lane = tid & 63;
  const int wr = wave >> 1, wc = wave & 1;
  const int lh = lane >> 4, ll = lane & 15;
  const int row_s = tid >> 3;
  const int kbp = (tid & 7) * 16;

  for (int kt = 0; kt < 48; ++kt) {
    __syncthreads();
#pragma unroll
    for (int st = 0; st < 4; ++st) {
      int row = st * 32 + row_s;
      int kb = kbp ^ ((row & 7) << 4);
      gload16((const char*)(Ap + (size_t)row * DIMC) + kt * 128 + kb,
              (char*)sm->A + st * 4096 + tid * 16);
      gload16((const char*)(Bp + (size_t)row * DIMC) + kt * 128 + kb,
              (char*)sm->B + st * 4096 + tid * 16);
    }
    __syncthreads();
#pragma unroll
    for (int ks = 0; ks < 2; ++ks) {
      s16x8 a[4], b[4];
#pragma unroll
      for (int f = 0; f < 4; ++f) {
        int ar = wr * 64 + f * 16 + ll;
        a[f] = *(const s16x8*)((const char*)sm->A + ar * 128 +
                               ((ks * 64 + lh * 16) ^ ((ar & 7) << 4)));
        int br = wc * 64 + f * 16 + ll;
        b[f] = *(const s16x8*)((const char*)sm->B + br * 128 +
                               ((ks * 64 + lh * 16) ^ ((br & 7) << 4)));
      }
#pragma unroll
      for (int i = 0; i < 4; i++)
#pragma unroll
        for (int j = 0; j < 4; j++)
          acc[i][j] = __builtin_amdgcn_mfma_f32_16x16x32_bf16(a[i], b[j], acc[i][j], 0, 0, 0);
    }
  }
  __syncthreads();
}

// ---------------- QKV GEMM + bias + RMSnorm + RoPE epilogue ----------------

union QkvSmem {
  StageSmem st;
  unsigned short ctile[128 * 136];
};

__global__ __launch_bounds__(256, 2) void qkv_gemm(
    const unsigned short* __restrict__ X, const unsigned short* __restrict__ WT,
    const float* __restrict__ bias, const float* __restrict__ wq,
    const float* __restrict__ wk, const float* __restrict__ freqs,
    unsigned short* __restrict__ Qb, unsigned short* __restrict__ Kb,
    unsigned short* __restrict__ Vt, int s_off) {
  __shared__ QkvSmem sm;
  const int tid = threadIdx.x;
  const int m0 = blockIdx.y * 128, n0 = blockIdx.x * 128;
  f32x4 acc[4][4] = {};
  gemm_core(X + (size_t)m0 * DIMC, WT + (size_t)n0 * DIMC, &sm.st, tid, acc);

  {
    const int wave = tid >> 6, lane = tid & 63;
    const int wr = wave >> 1, wc = wave & 1, lh = lane >> 4, ll = lane & 15;
#pragma unroll
    for (int fn = 0; fn < 4; ++fn) {
      int c = wc * 64 + fn * 16 + ll;
      float bv = bias[n0 + c];
#pragma unroll
      for (int fm = 0; fm < 4; ++fm)
#pragma unroll
        for (int j = 0; j < 4; j++) {
          int r = wr * 64 + fm * 16 + lh * 4 + j;
          sm.ctile[r * 136 + c] = f2bf(acc[fm][fn][j] + bv);
        }
    }
  }
  __syncthreads();

  const int qkv_idx = blockIdx.x / 24;
  const int head = blockIdx.x % 24;

  if (qkv_idx == 2) {
    const int sg0 = s_off + m0;
#pragma unroll
    for (int half = 0; half < 2; ++half) {
      int d = half * 64 + (tid >> 2);
      int t0 = (tid & 3) * 32;
      size_t obase = (size_t)(head * 128 + d) * S_TOT + sg0 + t0;
#pragma unroll
      for (int v = 0; v < 4; ++v) {
        u16x8 u;
#pragma unroll
        for (int i = 0; i < 8; i++) u[i] = sm.ctile[(t0 + v * 8 + i) * 136 + d];
        *(u16x8*)&Vt[obase + v * 8] = u;
      }
    }
  } else {
    const float* wn = (qkv_idx == 0) ? wq : wk;
    unsigned short* Ob = (qkv_idx == 0) ? Qb : Kb;
    const int row = tid >> 1, half = tid & 1;
    const int sg = s_off + m0 + row;
    float x[64];
    float ss = 0.f;
#pragma unroll
    for (int i = 0; i < 64; i++) {
      float v = bf2f(sm.ctile[row * 136 + half * 64 + i]);
      x[i] = v; ss += v * v;
    }
    ss += __shfl_xor(ss, 1);
    const float rn = rsqrtf(ss * (1.f / 128.f) + 1e-6f);
    const float* fr = freqs + (size_t)sg * 256 + half * 128;
    unsigned short o[64];
#pragma unroll
    for (int p = 0; p < 32; ++p) {
      float w0 = wn[half * 64 + 2 * p], w1 = wn[half * 64 + 2 * p + 1];
      float y0 = x[2 * p] * rn * w0, y1 = x[2 * p + 1] * rn * w1;
      float f00 = fr[p * 4], f01 = fr[p * 4 + 1], f10 = fr[p * 4 + 2], f11 = fr[p * 4 + 3];
      o[2 * p] = f2bf(f00 * y0 + f01 * y1);
      o[2 * p + 1] = f2bf(f10 * y0 + f11 * y1);
    }
    size_t ob = ((size_t)head * S_TOT + sg) * 128 + half * 64;
#pragma unroll
    for (int v = 0; v < 8; ++v) {
      u16x8 u;
#pragma unroll
      for (int i = 0; i < 8; i++) u[i] = o[v * 8 + i];
      *(u16x8*)&Ob[ob + v * 8] = u;
    }
  }
}

// ---------------- flash attention v2 ----------------
// 4 waves x 32 q-rows each (128 q/block), KV tile 64, grid 480 (co-resident).
// QK: 16x16x32 MFMA, B-frags shared across 2 q-rowblocks.
// PV: 32x32x16 MFMA via per-wave P tile [32][72] (bank-balanced pad).
// Softmax stats in QK row-in-lane layout; al/l crossed to PV row-in-reg
// layout via 128B per-wave LDS tables (read only on rescale tiles).

__global__ __launch_bounds__(256, 2) void attn_k(
    const unsigned short* __restrict__ Qb, const unsigned short* __restrict__ Kb,
    const unsigned short* __restrict__ Vt, unsigned short* __restrict__ AO) {
  __shared__ alignas(128) unsigned short Ks[2][64 * 128];  // [key][d] swizzled, dbuf
  __shared__ alignas(128) unsigned short Vs[128 * 64];     // [d][key] swizzled
  __shared__ alignas(128) unsigned short Ps[4][32 * 72];   // per-wave P [q][key]
  __shared__ float tabA[4][32];
  __shared__ float tabL[4][32];

  const int tid = threadIdx.x, w = tid >> 6, lane = tid & 63;
  const int lh = lane >> 4, ll16 = lane & 15;
  const int ll31 = lane & 31, hi = lane >> 5;
  // XCD-aware swizzle: 480 blocks, 8 XCDs -> 60 contiguous ids each = 3 heads.
  const int wgid = blockIdx.x;
  const int nid = (wgid & 7) * 60 + (wgid >> 3);
  const int h = nid / 20, qt = nid % 20;
  const float C = 0.12751744f;  // (1/sqrt(128)) * log2(e)

  // Q fragments: 2 rowblocks x 4 k-steps (16x16x32 A-frags)
  s16x8 qf[2][4];
#pragma unroll
  for (int rb = 0; rb < 2; rb++) {
    size_t qbase = ((size_t)h * S_TOT + qt * 128 + w * 32 + rb * 16 + ll16) * 128;
#pragma unroll
    for (int ks = 0; ks < 4; ks++) qf[rb][ks] = *(const s16x8*)&Qb[qbase + ks * 32 + lh * 8];
  }

  float m2[2][4], l_r[2][4];
  f32x16 o[4] = {};
#pragma unroll
  for (int rb = 0; rb < 2; rb++)
#pragma unroll
    for (int j = 0; j < 4; j++) { m2[rb][j] = -1e30f; l_r[rb][j] = 0.f; }

  const unsigned short* Kh = Kb + (size_t)h * S_TOT * 128;
  const unsigned short* Vh = Vt + (size_t)h * 128 * S_TOT;
  unsigned short* Pw = &Ps[w][0];

  // prologue: stage K tile 0 into buf 0
  {
#pragma unroll
    for (int st = 0; st < 4; ++st) {
      int row = st * 16 + (tid >> 4);
      int col = ((tid & 15) * 16) ^ ((row & 7) << 4);
      gload16((const char*)(Kh + (size_t)row * 128) + col,
              (char*)&Ks[0][0] + st * 4096 + tid * 16);
    }
  }

  int cur = 0;
  for (int kt = 0; kt < 40; ++kt) {
    __syncthreads();  // B1: K[cur] + (vmcnt drain); all waves done PV(kt-1)
    {   // stage V(kt) into single buffer (reads of PV(kt-1) done at B1)
      const int k0 = kt * 64;
#pragma unroll
      for (int st = 0; st < 4; ++st) {
        int row = st * 32 + (tid >> 3);
        int col = ((tid & 7) * 16) ^ ((row & 7) << 4);
        gload16((const char*)(Vh + (size_t)row * S_TOT + k0) + col,
                (char*)Vs + st * 4096 + tid * 16);
      }
    }
    if (kt + 1 < 40) {  // stage K(kt+1) into other buffer
      const unsigned short* Kn = Kh + (size_t)(kt + 1) * 64 * 128;
#pragma unroll
      for (int st = 0; st < 4; ++st) {
        int row = st * 16 + (tid >> 4);
        int col = ((tid & 15) * 16) ^ ((row & 7) << 4);
        gload16((const char*)(Kn + (size_t)row * 128) + col,
                (char*)&Ks[cur ^ 1][0] + st * 4096 + tid * 16);
      }
    }

    // ---- QK^T: 16 B-frag reads -> 32 MFMA ----
    const char* Kc = (const char*)&Ks[cur][0];
    f32x4 sc[2][4] = {};
#pragma unroll
    for (int kb = 0; kb < 4; kb++) {
      int krow = kb * 16 + ll16;
      const char* kr = Kc + krow * 256;
      int swz = (krow & 7) << 4;
#pragma unroll
      for (int ks = 0; ks < 4; ks++) {
        s16x8 bf = *(const s16x8*)(kr + ((ks * 64 + lh * 16) ^ swz));
        sc[0][kb] = __builtin_amdgcn_mfma_f32_16x16x32_bf16(qf[0][ks], bf, sc[0][kb], 0, 0, 0);
        sc[1][kb] = __builtin_amdgcn_mfma_f32_16x16x32_bf16(qf[1][ks], bf, sc[1][kb], 0, 0, 0);
      }
    }

    // ---- online softmax (QK layout: row = rb*16+lh*4+j, col = kb*16+ll16) ----
    float pmax[2][4];
#pragma unroll
    for (int rb = 0; rb < 2; rb++)
#pragma unroll
      for (int j = 0; j < 4; j++) {
        float v = fmaxf(fmaxf(sc[rb][0][j], sc[rb][1][j]), fmaxf(sc[rb][2][j], sc[rb][3][j]));
        pmax[rb][j] = rowmax16(v) * C;
      }
    bool need = false;
#pragma unroll
    for (int rb = 0; rb < 2; rb++)
#pragma unroll
      for (int j = 0; j < 4; j++) need |= (pmax[rb][j] > m2[rb][j] + 8.0f);
    if (__any(need)) {
#pragma unroll
      for (int rb = 0; rb < 2; rb++)
#pragma unroll
        for (int j = 0; j < 4; j++) {
          float mn = fmaxf(m2[rb][j], pmax[rb][j]);
          float al = exp2_fast(m2[rb][j] - mn);
          m2[rb][j] = mn;
          l_r[rb][j] *= al;
          if (ll16 == 0) tabA[w][rb * 16 + lh * 4 + j] = al;
        }
#pragma unroll
      for (int reg = 0; reg < 16; reg++) {
        int cr = (reg & 3) + 8 * (reg >> 2) + 4 * hi;
        float alv = tabA[w][cr];
        o[0][reg] *= alv; o[1][reg] *= alv; o[2][reg] *= alv; o[3][reg] *= alv;
      }
    }
#pragma unroll
    for (int rb = 0; rb < 2; rb++) {
      float ps0 = 0.f, ps1 = 0.f, ps2 = 0.f, ps3 = 0.f;
#pragma unroll
      for (int kb = 0; kb < 4; kb++) {
        float p0 = exp2_fast(sc[rb][kb][0] * C - m2[rb][0]);
        float p1 = exp2_fast(sc[rb][kb][1] * C - m2[rb][1]);
        float p2 = exp2_fast(sc[rb][kb][2] * C - m2[rb][2]);
        float p3 = exp2_fast(sc[rb][kb][3] * C - m2[rb][3]);
        ps0 += p0; ps1 += p1; ps2 += p2; ps3 += p3;
        int rbase = (rb * 16 + lh * 4);
        Pw[(rbase + 0) * 72 + kb * 16 + ll16] = f2bf(p0);
        Pw[(rbase + 1) * 72 + kb * 16 + ll16] = f2bf(p1);
        Pw[(rbase + 2) * 72 + kb * 16 + ll16] = f2bf(p2);
        Pw[(rbase + 3) * 72 + kb * 16 + ll16] = f2bf(p3);
      }
      l_r[rb][0] += rowsum16(ps0);
      l_r[rb][1] += rowsum16(ps1);
      l_r[rb][2] += rowsum16(ps2);
      l_r[rb][3] += rowsum16(ps3);
    }

    __syncthreads();  // B2: V(kt) arrived (vmcnt drain)

    // ---- PV: 32x32x16, A = P[32q x 16k], B = V[16k x 32d] ----
#pragma unroll
    for (int kstep = 0; kstep < 4; kstep++) {
      s16x8 pa = *(const s16x8*)((const char*)Pw + ll31 * 144 + kstep * 32 + hi * 16);
#pragma unroll
      for (int dblk = 0; dblk < 4; dblk++) {
        int vrow = dblk * 32 + ll31;
        s16x8 vb = *(const s16x8*)((const char*)Vs + vrow * 128 +
                                   ((kstep * 32 + hi * 16) ^ ((vrow & 7) << 4)));
        o[dblk] = __builtin_amdgcn_mfma_f32_32x32x16_bf16(pa, vb, o[dblk], 0, 0, 0);
      }
    }
    cur ^= 1;
  }

  // ---- epilogue: normalize by l (crossed via per-wave table) ----
  if (ll16 == 0) {
#pragma unroll
    for (int rb = 0; rb < 2; rb++)
#pragma unroll
      for (int j = 0; j < 4; j++) tabL[w][rb * 16 + lh * 4 + j] = l_r[rb][j];
  }
#pragma unroll
  for (int reg = 0; reg < 16; reg++) {
    int cr = (reg & 3) + 8 * (reg >> 2) + 4 * hi;
    float inv = 1.0f / tabL[w][cr];
    int srow = qt * 128 + w * 32 + cr;
    size_t base = (size_t)srow * DIMC + h * 128;
#pragma unroll
    for (int dblk = 0; dblk < 4; dblk++)
      AO[base + dblk * 32 + ll31] = f2bf(o[dblk][reg] * inv);
  }
}

// ---------------- out projection ----------------

__global__ __launch_bounds__(256, 2) void out_gemm(
    const unsigned short* __restrict__ A, const unsigned short* __restrict__ WT,
    const float* __restrict__ bias, float* __restrict__ C) {
  __shared__ StageSmem sm;
  const int tid = threadIdx.x;
  const int m0 = blockIdx.y * 128, n0 = blockIdx.x * 128;
  f32x4 acc[4][4] = {};
  gemm_core(A + (size_t)m0 * DIMC, WT + (size_t)n0 * DIMC, &sm, tid, acc);
  const int wave = tid >> 6, lane = tid & 63;
  const int wr = wave >> 1, wc = wave & 1, lh = lane >> 4, ll = lane & 15;
#pragma unroll
  for (int fn = 0; fn < 4; ++fn) {
    int c = n0 + wc * 64 + fn * 16 + ll;
    float bv = bias[c];
#pragma unroll
    for (int fm = 0; fm < 4; ++fm)
#pragma unroll
      for (int j = 0; j < 4; j++) {
        int r = m0 + wr * 64 + fm * 16 + lh * 4 + j;
        C[(size_t)r * DIMC + c] = acc[fm][fn][j] + bv;
      }
  }
}

// ---------------- launcher ----------------

extern "C" void kernel_launch(void* const* d_in, const int* in_sizes, int n_in,
                              void* d_out, int out_size, void* d_ws, size_t ws_size,
                              hipStream_t stream) {
  (void)in_sizes; (void)n_in; (void)out_size; (void)ws_size;
  const float* Xa = (const float*)d_in[0];
  const float* Xb = (const float*)d_in[1];
  const float* freqs = (const float*)d_in[2];
  const float* Wqkv_a = (const float*)d_in[3];
  const float* bqkv_a = (const float*)d_in[4];
  const float* Wqkv_b = (const float*)d_in[5];
  const float* bqkv_b = (const float*)d_in[6];
  const float* wq_a = (const float*)d_in[7];
  const float* wk_a = (const float*)d_in[8];
  const float* wq_b = (const float*)d_in[9];
  const float* wk_b = (const float*)d_in[10];
  const float* Wout_a = (const float*)d_in[11];
  const float* bout_a = (const float*)d_in[12];
  const float* Wout_b = (const float*)d_in[13];
  const float* bout_b = (const float*)d_in[14];
  float* out = (float*)d_out;

  char* ws = (char*)d_ws;
  unsigned short* WTa  = (unsigned short*)ws; ws += (size_t)NQKV * DIMC * 2;
  unsigned short* WTb  = (unsigned short*)ws; ws += (size_t)NQKV * DIMC * 2;
  unsigned short* WoTa = (unsigned short*)ws; ws += (size_t)DIMC * DIMC * 2;
  unsigned short* WoTb = (unsigned short*)ws; ws += (size_t)DIMC * DIMC * 2;
  unsigned short* Xa16 = (unsigned short*)ws; ws += (size_t)2048 * DIMC * 2;
  unsigned short* Xb16 = (unsigned short*)ws; ws += (size_t)512 * DIMC * 2;
  unsigned short* Qb   = (unsigned short*)ws; ws += (size_t)24 * S_TOT * 128 * 2;
  unsigned short* Kbf  = (unsigned short*)ws; ws += (size_t)24 * S_TOT * 128 * 2;
  unsigned short* Vt   = (unsigned short*)ws; ws += (size_t)24 * S_TOT * 128 * 2;
  unsigned short* AO   = (unsigned short*)ws; ws += (size_t)S_TOT * DIMC * 2;

  cvt_bf16_k<<<dim3(2048 * DIMC / 8 / 256), dim3(256), 0, stream>>>(Xa, Xa16, 2048 * DIMC / 8);
  cvt_bf16_k<<<dim3(512 * DIMC / 8 / 256), dim3(256), 0, stream>>>(Xb, Xb16, 512 * DIMC / 8);
  transpose_cvt<<<dim3(NQKV / 64, DIMC / 64), dim3(256), 0, stream>>>(Wqkv_a, WTa, DIMC, NQKV);
  transpose_cvt<<<dim3(NQKV / 64, DIMC / 64), dim3(256), 0, stream>>>(Wqkv_b, WTb, DIMC, NQKV);
  transpose_cvt<<<dim3(DIMC / 64, DIMC / 64), dim3(256), 0, stream>>>(Wout_a, WoTa, DIMC, DIMC);
  transpose_cvt<<<dim3(DIMC / 64, DIMC / 64), dim3(256), 0, stream>>>(Wout_b, WoTb, DIMC, DIMC);

  qkv_gemm<<<dim3(72, 16), dim3(256), 0, stream>>>(Xa16, WTa, bqkv_a, wq_a, wk_a, freqs,
                                                   Qb, Kbf, Vt, 512);
  qkv_gemm<<<dim3(72, 4), dim3(256), 0, stream>>>(Xb16, WTb, bqkv_b, wq_b, wk_b, freqs,
                                                  Qb, Kbf, Vt, 0);

  attn_k<<<dim3(480), dim3(256), 0, stream>>>(Qb, Kbf, Vt, AO);

  out_gemm<<<dim3(24, 16), dim3(256), 0, stream>>>(AO + (size_t)512 * DIMC, WoTa, bout_a, out);
  out_gemm<<<dim3(24, 4), dim3(256), 0, stream>>>(AO, WoTb, bout_b, out + (size_t)2048 * DIMC);
}